// Round 7
// baseline (99.687 us; speedup 1.0000x reference)
//
#include <hip/hip_runtime.h>
#include <math.h>

#define NFR 8
#define DD 2048
#define NS 25
#define NB 64
#define NPAIR (NS*NB)            // 1600
#define NITER 32
#define WS_TGT 640000            // float offset of tgt-gram region: 1600*4*100
#define SOLVE_BLKS 100

typedef __attribute__((ext_vector_type(4))) float f32x4;

// Branch-free acos, ~1e-7 rel (Cephes asinf core). Valid for |x| <= 1.
__device__ __forceinline__ float acos_fast(float x) {
    const float ax = fabsf(x);
    const bool big = ax > 0.5f;
    const float z = big ? 0.5f * (1.f - ax) : x * x;
    const float s = big ? sqrtf(z) : ax;
    float p = fmaf(z, 4.2163199048e-2f, 2.4181311049e-2f);
    p = fmaf(z, p, 4.5470025998e-2f);
    p = fmaf(z, p, 7.4953002686e-2f);
    p = fmaf(z, p, 1.6666752422e-1f);
    const float asin_s = fmaf(s * z, p, s);
    const float asin_abs = big ? (1.5707963267948966f - 2.f * asin_s) : asin_s;
    return 1.5707963267948966f - copysignf(asin_abs, x);
}

#define DOT4(acc, A, B) { acc = fmaf(A.x, B.x, acc); acc = fmaf(A.y, B.y, acc); \
                          acc = fmaf(A.z, B.z, acc); acc = fmaf(A.w, B.w, acc); }

__device__ __forceinline__ void bfly64(float& x) {
    #pragma unroll
    for (int m = 1; m <= 32; m <<= 1) x += __shfl_xor(x, m, 64);
}

// Async DMA: 64 lanes x 16B contiguous global -> contiguous LDS (wave-uniform dst).
__device__ __forceinline__ void load_lds16(const float* g, float* l) {
    __builtin_amdgcn_global_load_lds(
        (const __attribute__((address_space(1))) void*)g,
        (__attribute__((address_space(3))) void*)l, 16, 0, 0);
}

// Kernel 1: partial Grams.
//  Blocks 0..63: tgt-gram: block b, waves 0-3 = K-quarters, 36 accs -> ws tgt region.
//  Blocks 64..1343: main: (b, sq, kq). Stage tgt[b] K-quarter (16 KB) in LDS once;
//  wave w handles s = sq*5+w: 8 contiguous 1KB sup loads x2 chunks (all issued
//  up-front), lane-local f32 dot-partials for 36 supgram + 64 cross accs,
//  one 64-lane butterfly, dump 100 floats to private ws slot [p][kq][100].
__global__ __launch_bounds__(320) void gram_kernel(const float* __restrict__ sup,
                                                   const float* __restrict__ tgt,
                                                   float* __restrict__ ws) {
    const int bid = blockIdx.x;
    const int tid = threadIdx.x;
    const int wv  = tid >> 6;      // 0..4
    const int l   = tid & 63;

    __shared__ float tld[8 * 512];           // 16 KB: tgt rows, K-quarter

    if (bid < NB) {
        // ---- tgt-gram blocks ----
        if (wv < 4) {
            const int b = bid, kq = wv;
            const float* tb = tgt + (size_t)b * (NFR*DD) + kq * 512 + l * 4;
            float4 a0[8], a1[8];
            #pragma unroll
            for (int r = 0; r < 8; ++r) a0[r] = *(const float4*)(tb + r * DD);
            #pragma unroll
            for (int r = 0; r < 8; ++r) a1[r] = *(const float4*)(tb + r * DD + 256);
            float tss[36];
            #pragma unroll
            for (int i = 0; i < 36; ++i) tss[i] = 0.f;
            #pragma unroll
            for (int r1 = 0; r1 < 8; ++r1)
                #pragma unroll
                for (int r2 = r1; r2 < 8; ++r2) {
                    const int i = r1*8 + r2 - r1*(r1+1)/2;
                    DOT4(tss[i], a0[r1], a0[r2]);
                    DOT4(tss[i], a1[r1], a1[r2]);
                }
            #pragma unroll
            for (int i = 0; i < 36; ++i) bfly64(tss[i]);
            if (l == 0) {
                float4* o4 = (float4*)(ws + WS_TGT + (size_t)(b * 4 + kq) * 36);
                #pragma unroll
                for (int i = 0; i < 9; ++i)
                    o4[i] = make_float4(tss[4*i], tss[4*i+1], tss[4*i+2], tss[4*i+3]);
            }
        }
        return;
    }

    // ---- main blocks ----
    const int mb = bid - NB;
    const int b  = mb / 20;
    const int r20 = mb % 20;
    const int sq = r20 >> 2;
    const int kq = r20 & 3;
    const int s  = sq * 5 + wv;
    const int p  = s * NB + b;

    // Stage tgt[b] K-quarter: 16 segments of 1KB (row r, half h).
    for (int seg = wv; seg < 16; seg += 5) {
        const int r = seg >> 1, h = seg & 1;
        load_lds16(tgt + ((size_t)b * NFR + r) * DD + kq * 512 + h * 256 + l * 4,
                   tld + r * 512 + h * 256);
    }
    __syncthreads();

    const float* sb = sup + (size_t)p * (NFR*DD) + kq * 512 + l * 4;
    float4 sv0[8], sv1[8];
    #pragma unroll
    for (int r = 0; r < 8; ++r) sv0[r] = *(const float4*)(sb + r * DD);
    #pragma unroll
    for (int r = 0; r < 8; ++r) sv1[r] = *(const float4*)(sb + r * DD + 256);

    float ass[36], ax[64];
    #pragma unroll
    for (int i = 0; i < 36; ++i) ass[i] = 0.f;
    #pragma unroll
    for (int i = 0; i < 64; ++i) ax[i] = 0.f;

    float4 tv[8];
    #pragma unroll
    for (int r = 0; r < 8; ++r) tv[r] = *(const float4*)(tld + r * 512 + l * 4);
    #pragma unroll
    for (int r1 = 0; r1 < 8; ++r1)
        #pragma unroll
        for (int r2 = r1; r2 < 8; ++r2) {
            const int i = r1*8 + r2 - r1*(r1+1)/2;
            DOT4(ass[i], sv0[r1], sv0[r2]);
        }
    #pragma unroll
    for (int r = 0; r < 8; ++r)
        #pragma unroll
        for (int t = 0; t < 8; ++t) DOT4(ax[r*8+t], sv0[r], tv[t]);

    #pragma unroll
    for (int r = 0; r < 8; ++r) tv[r] = *(const float4*)(tld + r * 512 + 256 + l * 4);
    #pragma unroll
    for (int r1 = 0; r1 < 8; ++r1)
        #pragma unroll
        for (int r2 = r1; r2 < 8; ++r2) {
            const int i = r1*8 + r2 - r1*(r1+1)/2;
            DOT4(ass[i], sv1[r1], sv1[r2]);
        }
    #pragma unroll
    for (int r = 0; r < 8; ++r)
        #pragma unroll
        for (int t = 0; t < 8; ++t) DOT4(ax[r*8+t], sv1[r], tv[t]);

    #pragma unroll
    for (int i = 0; i < 36; ++i) bfly64(ass[i]);
    #pragma unroll
    for (int i = 0; i < 64; ++i) bfly64(ax[i]);

    if (l == 0) {
        float4* o4 = (float4*)(ws + (size_t)(p * 4 + kq) * 100);
        #pragma unroll
        for (int i = 0; i < 9; ++i)
            o4[i] = make_float4(ass[4*i], ass[4*i+1], ass[4*i+2], ass[4*i+3]);
        #pragma unroll
        for (int i = 0; i < 16; ++i)
            o4[9+i] = make_float4(ax[4*i], ax[4*i+1], ax[4*i+2], ax[4*i+3]);
    }
}

// Kernel 2: build 16x16 synth Gram per pair from ws partials, then the verified
// 16-lane Frechet solve (lanes 0-7 support, 8-15 target), 16 pairs per block.
__global__ __launch_bounds__(256) void solve_kernel(const float* __restrict__ ws,
                                                    float* __restrict__ out) {
    const int bid = blockIdx.x;
    const int tid = threadIdx.x;
    __shared__ float synth[16 * 256];

    for (int e = tid; e < 4096; e += 256) {
        const int pp = e >> 8, ij = e & 255;
        const int i = ij >> 4, j = ij & 15;
        const int p = bid * 16 + pp;
        const int b = p & (NB - 1);
        float v = 0.f;
        if (i < 8) {
            if (j < 8) {
                const int ii = i < j ? i : j, jj = i < j ? j : i;
                const int t36 = ii*8 + jj - ii*(ii+1)/2;
                #pragma unroll
                for (int kq = 0; kq < 4; ++kq) v += ws[(size_t)(p*4+kq)*100 + t36];
            } else {
                #pragma unroll
                for (int kq = 0; kq < 4; ++kq) v += ws[(size_t)(p*4+kq)*100 + 36 + i*8 + (j-8)];
            }
        } else if (j >= 8) {
            const int i8 = i - 8, j8 = j - 8;
            const int ii = i8 < j8 ? i8 : j8, jj = i8 < j8 ? j8 : i8;
            const int t36 = ii*8 + jj - ii*(ii+1)/2;
            #pragma unroll
            for (int kq = 0; kq < 4; ++kq) v += ws[WS_TGT + (size_t)(b*4+kq)*36 + t36];
        }
        synth[e] = v;
    }
    __syncthreads();

    const int pp = tid >> 4;
    const int t16 = tid & 15;
    const int p = bid * 16 + pp;
    const float* graw = synth + pp * 256;
    const int j = t16 & 7;
    const int base = t16 & 8;              // 0 = sup half, 8 = tgt half
    const int R = base + j;
    const int cb = base;

    const float invn_own = rsqrtf(fmaxf(graw[R * 16 + R], 1e-14f));
    float Grow[8];
    #pragma unroll
    for (int k = 0; k < 8; ++k) {
        const float invk = rsqrtf(fmaxf(graw[(cb + k) * 16 + (cb + k)], 1e-14f));
        Grow[k] = graw[R * 16 + cb + k] * invn_own * invk;
    }

    // mu0 = normalize(mean X^): a_k = rsqrt(sum G)
    float rs = 0.f;
    #pragma unroll
    for (int k = 0; k < 8; ++k) rs += Grow[k];
    rs += __shfl_xor(rs, 1, 8);
    rs += __shfl_xor(rs, 2, 8);
    rs += __shfl_xor(rs, 4, 8);
    float a_own = rsqrtf(fmaxf(rs, 6.4e-13f));
    float aAll[8];
    #pragma unroll
    for (int k = 0; k < 8; ++k) aAll[k] = a_own;

    for (int it = 0; it < NITER; ++it) {
        float dot = 0.f;
        #pragma unroll
        for (int k = 0; k < 8; ++k) dot = fmaf(Grow[k], aAll[k], dot);
        dot = fminf(fmaxf(dot, -1.f + 1e-6f), 1.f - 1e-6f);
        const float theta = acos_fast(dot);
        const float q = fmaf(-dot, dot, 1.0f);          // sin^2(theta)
        const float coef = (theta > 1e-4f) ? theta * rsqrtf(q) : 1.f;
        const float w = 0.125f * coef;
        float wAll[8];
        #pragma unroll
        for (int k = 0; k < 8; ++k) wAll[k] = __shfl(w, base + k, 16);
        float Gw = 0.f;
        #pragma unroll
        for (int k = 0; k < 8; ++k) Gw = fmaf(Grow[k], wAll[k], Gw);
        // two interleaved 8-lane reductions: cdavg = a^T G w, wGw = w^T G w
        float u1 = a_own * Gw, u2 = w * Gw;
        u1 += __shfl_xor(u1, 1, 8);  u2 += __shfl_xor(u2, 1, 8);
        u1 += __shfl_xor(u1, 2, 8);  u2 += __shfl_xor(u2, 2, 8);
        u1 += __shfl_xor(u1, 4, 8);  u2 += __shfl_xor(u2, 4, 8);
        const float cdavg = u1;
        const float vnsq = fmaxf(u2 - cdavg * cdavg, 0.f);   // ||v||^2
        const float vn = sqrtf(vnsq);
        const float rev = vn * 0.15915494309189535f;
        const float sinv = __builtin_amdgcn_sinf(rev);       // sin(vn)
        const float cosv = __builtin_amdgcn_cosf(rev);       // cos(vn)
        const float sinc = (vn > 1e-9f) ? sinv / vn : 1.f;
        // ||mu_new||^2 = cos^2 + sinc^2 * ||v||^2  (a^T G b = 0 algebraically)
        const float cn2 = fmaf(sinc * sinc, vnsq, cosv * cosv);
        const float rn = rsqrtf(fmaxf(cn2, 1e-14f));
        a_own = (cosv * a_own + sinc * fmaf(-cdavg, a_own, w)) * rn;
        #pragma unroll
        for (int k = 0; k < 8; ++k)
            aAll[k] = (cosv * aAll[k] + sinc * fmaf(-cdavg, aAll[k], wAll[k])) * rn;
    }

    // sim = sum_{j,l} ahat_sup_j * Craw[j][l] * ahat_tgt_l
    const float ahat = a_own * invn_own;
    float at[8];
    #pragma unroll
    for (int q2 = 0; q2 < 8; ++q2) at[q2] = __shfl(ahat, 8 + q2, 16);
    float tacc = 0.f;
    #pragma unroll
    for (int q2 = 0; q2 < 8; ++q2) tacc = fmaf(graw[j * 16 + 8 + q2], at[q2], tacc);
    float sim = ahat * tacc;
    sim += __shfl_xor(sim, 1, 8);
    sim += __shfl_xor(sim, 2, 8);
    sim += __shfl_xor(sim, 4, 8);
    if (t16 == 0) out[p] = sim;
}

extern "C" void kernel_launch(void* const* d_in, const int* in_sizes, int n_in,
                              void* d_out, int out_size, void* d_ws, size_t ws_size,
                              hipStream_t stream) {
    const float* sup = (const float*)d_in[0];   // [25,64,8,2048] f32
    const float* tgt = (const float*)d_in[1];   // [64,8,2048] f32
    float* ws = (float*)d_ws;                   // needs 649216 floats = 2.6 MB
    float* out = (float*)d_out;                 // [25,64] f32
    gram_kernel<<<NB + NB * 20, 320, 0, stream>>>(sup, tgt, ws);
    solve_kernel<<<SOLVE_BLKS, 256, 0, stream>>>(ws, out);
}

// Round 8
// 61.829 us; speedup vs baseline: 1.6123x; 1.6123x over previous
//
#include <hip/hip_runtime.h>
#include <math.h>

#define NFR 8
#define DD 2048
#define NS 25
#define NB 64
#define NPAIR (NS*NB)          // 1600
#define NITER 32
#define TILE 256               // k-floats per tile
#define NT (DD/TILE)           // 8 tiles
#define RSTRIDE 260            // LDS row stride in floats (1040 B, 16B-aligned)
#define BUFSZ (16*RSTRIDE)     // 4160 floats per buffer

typedef __attribute__((ext_vector_type(8))) short short8;
typedef __attribute__((ext_vector_type(4))) float f32x4;

// Branch-free acos, ~1e-7 rel (Cephes asinf core). Valid for |x| <= 1.
__device__ __forceinline__ float acos_fast(float x) {
    const float ax = fabsf(x);
    const bool big = ax > 0.5f;
    const float z = big ? 0.5f * (1.f - ax) : x * x;
    const float s = big ? sqrtf(z) : ax;
    float p = fmaf(z, 4.2163199048e-2f, 2.4181311049e-2f);
    p = fmaf(z, p, 4.5470025998e-2f);
    p = fmaf(z, p, 7.4953002686e-2f);
    p = fmaf(z, p, 1.6666752422e-1f);
    const float asin_s = fmaf(s * z, p, s);
    const float asin_abs = big ? (1.5707963267948966f - 2.f * asin_s) : asin_s;
    return 1.5707963267948966f - copysignf(asin_abs, x);
}

// Pack hi-bf16 of (a,b) and lo-bf16 remainders via v_perm_b32.
#define SPLIT2(a, b, HI, LO) { \
    const float ha_ = __uint_as_float(__float_as_uint(a) & 0xFFFF0000u); \
    const float hb_ = __uint_as_float(__float_as_uint(b) & 0xFFFF0000u); \
    HI = __builtin_amdgcn_perm(__float_as_uint(b), __float_as_uint(a), 0x07060302u); \
    LO = __builtin_amdgcn_perm(__float_as_uint((b) - hb_), __float_as_uint((a) - ha_), 0x07060302u); \
}

// Async DMA: 64 lanes x 16B -> 1KB contiguous LDS (wave-uniform dst base).
__device__ __forceinline__ void load_lds16(const float* g, float* l) {
    __builtin_amdgcn_global_load_lds(
        (const __attribute__((address_space(1))) void*)g,
        (__attribute__((address_space(3))) void*)l, 16, 0, 0);
}

// One block (4 waves) per (s,b) pair.
// Phase 1: double-buffered LDS staging. Per tile: 16 DMA instructions, each a
//   LINEAR 1KB burst (one row's 256-float chunk) -> DRAM/L2-friendly. Waves
//   split each tile's K 4 ways; bf16 hi/lo MFMA Gram of [8 sup; 8 tgt] rows.
// Phase 2: LDS-reduce 4 partials -> 16x16 Gram; verified 16-lane Frechet solve.
__global__ __launch_bounds__(256) void fused_kernel(const float* __restrict__ sup,
                                                    const float* __restrict__ tgt,
                                                    float* __restrict__ out) {
    const int p   = blockIdx.x;
    const int b   = p & (NB - 1);
    const int tid = threadIdx.x;
    const int wv  = tid >> 6;      // 0..3
    const int l   = tid & 63;
    const int row = l & 15;
    const int kg  = l >> 4;

    __shared__ float lds[2 * BUFSZ];         // 33280 B
    float* part = lds;                       // overlay after streaming
    float* graw = lds + 2176;

    // This wave stages rows r = wv + 4*i (i=0..3): linear 1KB per DMA.
    const float* srow[4];
    #pragma unroll
    for (int i = 0; i < 4; ++i) {
        const int r = wv + 4 * i;
        srow[i] = (r < 8) ? sup + ((size_t)p * NFR + r) * DD + l * 4
                          : tgt + ((size_t)b * NFR + (r - 8)) * DD + l * 4;
    }

    f32x4 accA = {0.f, 0.f, 0.f, 0.f};
    f32x4 accB = {0.f, 0.f, 0.f, 0.f};

    // Prologue: stage tile 0 into buf0.
    #pragma unroll
    for (int i = 0; i < 4; ++i)
        load_lds16(srow[i], lds + (wv + 4 * i) * RSTRIDE);
    __syncthreads();

    #pragma unroll
    for (int t = 0; t < NT; ++t) {
        if (t + 1 < NT) {
            float* dbuf = lds + ((t + 1) & 1) * BUFSZ;
            #pragma unroll
            for (int i = 0; i < 4; ++i)
                load_lds16(srow[i] + (t + 1) * TILE, dbuf + (wv + 4 * i) * RSTRIDE);
        }
        const float* fb = lds + (t & 1) * BUFSZ + row * RSTRIDE + wv * 64 + kg * 8;
        #pragma unroll
        for (int c2 = 0; c2 < 2; ++c2) {
            const float4 f0 = *(const float4*)(fb + c2 * 32);
            const float4 f1 = *(const float4*)(fb + c2 * 32 + 4);
            union { unsigned int u[4]; short8 s8; } H, L;
            SPLIT2(f0.x, f0.y, H.u[0], L.u[0]);
            SPLIT2(f0.z, f0.w, H.u[1], L.u[1]);
            SPLIT2(f1.x, f1.y, H.u[2], L.u[2]);
            SPLIT2(f1.z, f1.w, H.u[3], L.u[3]);
            accA = __builtin_amdgcn_mfma_f32_16x16x32_bf16(H.s8, H.s8, accA, 0, 0, 0);
            accB = __builtin_amdgcn_mfma_f32_16x16x32_bf16(H.s8, L.s8, accB, 0, 0, 0);
            accB = __builtin_amdgcn_mfma_f32_16x16x32_bf16(L.s8, H.s8, accB, 0, 0, 0);
        }
        __syncthreads();
    }

    // Dump per-wave partials (overlays buf0, dead since tile NT-2; last barrier passed).
    #pragma unroll
    for (int r = 0; r < 4; ++r)
        part[wv * 272 + (kg * 4 + r) * 17 + row] = accA[r] + accB[r];
    __syncthreads();

    {
        const int rr = tid >> 4, cc = tid & 15;
        float s = part[rr * 17 + cc] + part[272 + rr * 17 + cc]
                + part[544 + rr * 17 + cc] + part[816 + rr * 17 + cc];
        __syncthreads();
        graw[rr * 16 + cc] = s;
    }
    __syncthreads();

    if (tid < 16) {
        const int j = tid & 7;
        const int base = tid & 8;              // 0 = sup half, 8 = tgt half
        const int R = base + j;
        const int cb = base;

        const float invn_own = rsqrtf(fmaxf(graw[R * 16 + R], 1e-14f));
        float Grow[8];
        #pragma unroll
        for (int k = 0; k < 8; ++k) {
            const float invk = rsqrtf(fmaxf(graw[(cb + k) * 16 + (cb + k)], 1e-14f));
            Grow[k] = graw[R * 16 + cb + k] * invn_own * invk;
        }

        // mu0 = normalize(mean X^): a_k = rsqrt(sum G)
        float rs = 0.f;
        #pragma unroll
        for (int k = 0; k < 8; ++k) rs += Grow[k];
        rs += __shfl_xor(rs, 1, 8);
        rs += __shfl_xor(rs, 2, 8);
        rs += __shfl_xor(rs, 4, 8);
        float a_own = rsqrtf(fmaxf(rs, 6.4e-13f));
        float aAll[8];
        #pragma unroll
        for (int k = 0; k < 8; ++k) aAll[k] = a_own;

        for (int it = 0; it < NITER; ++it) {
            float dot = 0.f;
            #pragma unroll
            for (int k = 0; k < 8; ++k) dot = fmaf(Grow[k], aAll[k], dot);
            dot = fminf(fmaxf(dot, -1.f + 1e-6f), 1.f - 1e-6f);
            const float theta = acos_fast(dot);
            const float q = fmaf(-dot, dot, 1.0f);          // sin^2(theta)
            const float coef = (theta > 1e-4f) ? theta * rsqrtf(q) : 1.f;
            const float w = 0.125f * coef;
            float wAll[8];
            #pragma unroll
            for (int k = 0; k < 8; ++k) wAll[k] = __shfl(w, base + k, 16);
            float Gw = 0.f;
            #pragma unroll
            for (int k = 0; k < 8; ++k) Gw = fmaf(Grow[k], wAll[k], Gw);
            // two interleaved 8-lane reductions: cdavg = a^T G w, wGw = w^T G w
            float u1 = a_own * Gw, u2 = w * Gw;
            u1 += __shfl_xor(u1, 1, 8);  u2 += __shfl_xor(u2, 1, 8);
            u1 += __shfl_xor(u1, 2, 8);  u2 += __shfl_xor(u2, 2, 8);
            u1 += __shfl_xor(u1, 4, 8);  u2 += __shfl_xor(u2, 4, 8);
            const float cdavg = u1;
            const float vnsq = fmaxf(u2 - cdavg * cdavg, 0.f);   // ||v||^2
            const float vn = sqrtf(vnsq);
            const float rev = vn * 0.15915494309189535f;
            const float sinv = __builtin_amdgcn_sinf(rev);       // sin(vn)
            const float cosv = __builtin_amdgcn_cosf(rev);       // cos(vn)
            const float sinc = (vn > 1e-9f) ? sinv / vn : 1.f;
            // ||mu_new||^2 = cos^2 + sinc^2 * ||v||^2  (a^T G b = 0 algebraically)
            const float cn2 = fmaf(sinc * sinc, vnsq, cosv * cosv);
            const float rn = rsqrtf(fmaxf(cn2, 1e-14f));
            a_own = (cosv * a_own + sinc * fmaf(-cdavg, a_own, w)) * rn;
            #pragma unroll
            for (int k = 0; k < 8; ++k)
                aAll[k] = (cosv * aAll[k] + sinc * fmaf(-cdavg, aAll[k], wAll[k])) * rn;
        }

        // sim = sum_{j,l} ahat_sup_j * Craw[j][l] * ahat_tgt_l
        const float ahat = a_own * invn_own;
        float at[8];
        #pragma unroll
        for (int q2 = 0; q2 < 8; ++q2) at[q2] = __shfl(ahat, 8 + q2, 16);
        float tacc = 0.f;
        #pragma unroll
        for (int q2 = 0; q2 < 8; ++q2) tacc = fmaf(graw[j * 16 + 8 + q2], at[q2], tacc);
        float sim = ahat * tacc;
        sim += __shfl_xor(sim, 1, 8);
        sim += __shfl_xor(sim, 2, 8);
        sim += __shfl_xor(sim, 4, 8);
        if (tid == 0) out[p] = sim;
    }
}

extern "C" void kernel_launch(void* const* d_in, const int* in_sizes, int n_in,
                              void* d_out, int out_size, void* d_ws, size_t ws_size,
                              hipStream_t stream) {
    const float* sup = (const float*)d_in[0];   // [25,64,8,2048] f32
    const float* tgt = (const float*)d_in[1];   // [64,8,2048] f32
    float* out = (float*)d_out;                 // [25,64] f32
    fused_kernel<<<NPAIR, 256, 0, stream>>>(sup, tgt, out);
}

// Round 9
// 53.104 us; speedup vs baseline: 1.8772x; 1.1643x over previous
//
#include <hip/hip_runtime.h>
#include <math.h>

#define NFR 8
#define DD 2048
#define NS 25
#define NB 64
#define NPAIR (NS*NB)          // 1600
#define NITER 32
#define WS_TGT 320000          // float offset of tgt region: 1600*2*100
#define SOLVE_BLKS 100

typedef __attribute__((ext_vector_type(8))) short short8;
typedef __attribute__((ext_vector_type(4))) float f32x4;

// Branch-free acos, ~1e-7 rel (Cephes asinf core). Valid for |x| <= 1.
__device__ __forceinline__ float acos_fast(float x) {
    const float ax = fabsf(x);
    const bool big = ax > 0.5f;
    const float z = big ? 0.5f * (1.f - ax) : x * x;
    const float s = big ? sqrtf(z) : ax;
    float p = fmaf(z, 4.2163199048e-2f, 2.4181311049e-2f);
    p = fmaf(z, p, 4.5470025998e-2f);
    p = fmaf(z, p, 7.4953002686e-2f);
    p = fmaf(z, p, 1.6666752422e-1f);
    const float asin_s = fmaf(s * z, p, s);
    const float asin_abs = big ? (1.5707963267948966f - 2.f * asin_s) : asin_s;
    return 1.5707963267948966f - copysignf(asin_abs, x);
}

// Pack hi-bf16 of (a,b) and lo-bf16 remainders via v_perm_b32.
#define SPLIT2(a, b, HI, LO) { \
    const float ha_ = __uint_as_float(__float_as_uint(a) & 0xFFFF0000u); \
    const float hb_ = __uint_as_float(__float_as_uint(b) & 0xFFFF0000u); \
    HI = __builtin_amdgcn_perm(__float_as_uint(b), __float_as_uint(a), 0x07060302u); \
    LO = __builtin_amdgcn_perm(__float_as_uint((b) - hb_), __float_as_uint((a) - ha_), 0x07060302u); \
}

// Async DMA: 64 lanes x 16B -> 1KB contiguous LDS (wave-uniform dst base).
__device__ __forceinline__ void load_lds16(const float* g, float* l) {
    __builtin_amdgcn_global_load_lds(
        (const __attribute__((address_space(1))) void*)g,
        (__attribute__((address_space(3))) void*)l, 16, 0, 0);
}

// One block (8 waves) per (pair, K-half). ALL 64 DMAs (64KB) issued up-front,
// ONE drain, then barrier-free MFMA Gram of [8 sup; 8 tgt] rows from LDS.
// LDS rows XOR-swizzled (source-side inverse + read-side XOR, involution) so
// ds_read_b128 lands 8 lanes per 16B slot (optimal). Partials -> ws.
// Grid swizzled so each XCD owns 8 b's (tgt L2-resident per XCD).
__global__ __launch_bounds__(512) void gram_kernel(const float* __restrict__ sup,
                                                   const float* __restrict__ tgt,
                                                   float* __restrict__ ws) {
    const int bid = blockIdx.x;
    const int xcd = bid & 7;
    const int q   = bid >> 3;           // 0..399
    const int b   = xcd * 8 + (q & 7);
    const int sq  = q >> 3;             // 0..49
    const int s   = sq % NS;
    const int kh  = sq / NS;            // 0,1
    const int p   = s * NB + b;
    const int tid = threadIdx.x;
    const int wv  = tid >> 6;           // 0..7
    const int l   = tid & 63;
    const int row = l & 15;
    const int kg  = l >> 4;

    __shared__ float lds[16384];        // 64 KB: 16 rows x 1024 f32, XOR-swizzled

    // Stage: wave wv stages rows 2wv, 2wv+1. Source pre-swizzled by (l ^ (r&7)).
    #pragma unroll
    for (int i = 0; i < 2; ++i) {
        const int r  = 2 * wv + i;
        const int r7 = r & 7;
        const float* g = (r < 8)
            ? sup + ((size_t)p * NFR + r) * DD + kh * 1024
            : tgt + ((size_t)b * NFR + (r - 8)) * DD + kh * 1024;
        const float* gl = g + (size_t)((l ^ r7) * 4);
        float* d = lds + r * 1024;
        #pragma unroll
        for (int c = 0; c < 4; ++c)
            load_lds16(gl + c * 256, d + c * 256);
    }
    __syncthreads();                    // single vmcnt drain for all 64 DMAs

    // Compute: wave wv owns k in [wv*128, wv*128+128) of this half. No barriers.
    f32x4 accA = {0.f, 0.f, 0.f, 0.f};
    f32x4 accB = {0.f, 0.f, 0.f, 0.f};
    const int swz = (row & 7) << 4;
    const char* rowbase = (const char*)lds + row * 4096;
    #pragma unroll
    for (int st = 0; st < 4; ++st) {
        const int o0 = (wv * 128 + st * 32) * 4 + kg * 32;
        const float4 f0 = *(const float4*)(rowbase + (o0 ^ swz));
        const float4 f1 = *(const float4*)(rowbase + ((o0 + 16) ^ swz));
        union { unsigned int u[4]; short8 s8; } H, L;
        SPLIT2(f0.x, f0.y, H.u[0], L.u[0]);
        SPLIT2(f0.z, f0.w, H.u[1], L.u[1]);
        SPLIT2(f1.x, f1.y, H.u[2], L.u[2]);
        SPLIT2(f1.z, f1.w, H.u[3], L.u[3]);
        accA = __builtin_amdgcn_mfma_f32_16x16x32_bf16(H.s8, H.s8, accA, 0, 0, 0);
        accB = __builtin_amdgcn_mfma_f32_16x16x32_bf16(H.s8, L.s8, accB, 0, 0, 0);
        accB = __builtin_amdgcn_mfma_f32_16x16x32_bf16(L.s8, H.s8, accB, 0, 0, 0);
    }
    __syncthreads();                    // all LDS reads done; safe to overlay

    // Per-wave partials: D[(l>>4)*4+r][l&15] (same verified convention).
    float* part = lds;
    #pragma unroll
    for (int r = 0; r < 4; ++r)
        part[wv * 272 + (kg * 4 + r) * 17 + row] = accA[r] + accB[r];
    __syncthreads();

    // Reduce 8 partials and dump compact 100 (+36 tgt if s==0) to ws.
    if (tid < 256) {
        const int rr = tid >> 4, cc = tid & 15;
        float v = 0.f;
        #pragma unroll
        for (int w = 0; w < 8; ++w) v += part[w * 272 + rr * 17 + cc];
        if (rr < 8) {
            if (cc >= 8)
                ws[(size_t)(p * 2 + kh) * 100 + 36 + rr * 8 + (cc - 8)] = v;
            else if (cc >= rr)
                ws[(size_t)(p * 2 + kh) * 100 + rr * 8 + cc - rr * (rr + 1) / 2] = v;
        } else if (s == 0 && cc >= rr) {
            const int i8 = rr - 8, j8 = cc - 8;
            ws[WS_TGT + (size_t)(b * 2 + kh) * 36 + i8 * 8 + j8 - i8 * (i8 + 1) / 2] = v;
        }
    }
}

// Kernel 2: rebuild 16x16 synth Gram per pair from ws partials, then the
// verified 16-lane Frechet solve (lanes 0-7 support, 8-15 target), 16 pairs/blk.
__global__ __launch_bounds__(256) void solve_kernel(const float* __restrict__ ws,
                                                    float* __restrict__ out) {
    const int bid = blockIdx.x;
    const int tid = threadIdx.x;
    __shared__ float synth[16 * 256];

    for (int e = tid; e < 4096; e += 256) {
        const int pp = e >> 8, ij = e & 255;
        const int i = ij >> 4, j = ij & 15;
        const int p = bid * 16 + pp;
        const int b = p & (NB - 1);
        float v = 0.f;
        if (i < 8) {
            if (j < 8) {
                const int ii = i < j ? i : j, jj = i < j ? j : i;
                const int t36 = ii*8 + jj - ii*(ii+1)/2;
                v = ws[(size_t)(p*2+0)*100 + t36] + ws[(size_t)(p*2+1)*100 + t36];
            } else {
                const int c64 = 36 + i*8 + (j-8);
                v = ws[(size_t)(p*2+0)*100 + c64] + ws[(size_t)(p*2+1)*100 + c64];
            }
        } else if (j >= 8) {
            const int i8 = i - 8, j8 = j - 8;
            const int ii = i8 < j8 ? i8 : j8, jj = i8 < j8 ? j8 : i8;
            const int t36 = ii*8 + jj - ii*(ii+1)/2;
            v = ws[WS_TGT + (size_t)(b*2+0)*36 + t36] + ws[WS_TGT + (size_t)(b*2+1)*36 + t36];
        }
        synth[e] = v;
    }
    __syncthreads();

    const int pp = tid >> 4;
    const int t16 = tid & 15;
    const int p = bid * 16 + pp;
    const float* graw = synth + pp * 256;
    const int j = t16 & 7;
    const int base = t16 & 8;              // 0 = sup half, 8 = tgt half
    const int R = base + j;
    const int cb = base;

    const float invn_own = rsqrtf(fmaxf(graw[R * 16 + R], 1e-14f));
    float Grow[8];
    #pragma unroll
    for (int k = 0; k < 8; ++k) {
        const float invk = rsqrtf(fmaxf(graw[(cb + k) * 16 + (cb + k)], 1e-14f));
        Grow[k] = graw[R * 16 + cb + k] * invn_own * invk;
    }

    // mu0 = normalize(mean X^): a_k = rsqrt(sum G)
    float rs = 0.f;
    #pragma unroll
    for (int k = 0; k < 8; ++k) rs += Grow[k];
    rs += __shfl_xor(rs, 1, 8);
    rs += __shfl_xor(rs, 2, 8);
    rs += __shfl_xor(rs, 4, 8);
    float a_own = rsqrtf(fmaxf(rs, 6.4e-13f));
    float aAll[8];
    #pragma unroll
    for (int k = 0; k < 8; ++k) aAll[k] = a_own;

    for (int it = 0; it < NITER; ++it) {
        float dot = 0.f;
        #pragma unroll
        for (int k = 0; k < 8; ++k) dot = fmaf(Grow[k], aAll[k], dot);
        dot = fminf(fmaxf(dot, -1.f + 1e-6f), 1.f - 1e-6f);
        const float theta = acos_fast(dot);
        const float q = fmaf(-dot, dot, 1.0f);          // sin^2(theta)
        const float coef = (theta > 1e-4f) ? theta * rsqrtf(q) : 1.f;
        const float w = 0.125f * coef;
        float wAll[8];
        #pragma unroll
        for (int k = 0; k < 8; ++k) wAll[k] = __shfl(w, base + k, 16);
        float Gw = 0.f;
        #pragma unroll
        for (int k = 0; k < 8; ++k) Gw = fmaf(Grow[k], wAll[k], Gw);
        // two interleaved 8-lane reductions: cdavg = a^T G w, wGw = w^T G w
        float u1 = a_own * Gw, u2 = w * Gw;
        u1 += __shfl_xor(u1, 1, 8);  u2 += __shfl_xor(u2, 1, 8);
        u1 += __shfl_xor(u1, 2, 8);  u2 += __shfl_xor(u2, 2, 8);
        u1 += __shfl_xor(u1, 4, 8);  u2 += __shfl_xor(u2, 4, 8);
        const float cdavg = u1;
        const float vnsq = fmaxf(u2 - cdavg * cdavg, 0.f);   // ||v||^2
        const float vn = sqrtf(vnsq);
        const float rev = vn * 0.15915494309189535f;
        const float sinv = __builtin_amdgcn_sinf(rev);       // sin(vn)
        const float cosv = __builtin_amdgcn_cosf(rev);       // cos(vn)
        const float sinc = (vn > 1e-9f) ? sinv / vn : 1.f;
        // ||mu_new||^2 = cos^2 + sinc^2 * ||v||^2  (a^T G b = 0 algebraically)
        const float cn2 = fmaf(sinc * sinc, vnsq, cosv * cosv);
        const float rn = rsqrtf(fmaxf(cn2, 1e-14f));
        a_own = (cosv * a_own + sinc * fmaf(-cdavg, a_own, w)) * rn;
        #pragma unroll
        for (int k = 0; k < 8; ++k)
            aAll[k] = (cosv * aAll[k] + sinc * fmaf(-cdavg, aAll[k], wAll[k])) * rn;
    }

    // sim = sum_{j,l} ahat_sup_j * Craw[j][l] * ahat_tgt_l
    const float ahat = a_own * invn_own;
    float at[8];
    #pragma unroll
    for (int q2 = 0; q2 < 8; ++q2) at[q2] = __shfl(ahat, 8 + q2, 16);
    float tacc = 0.f;
    #pragma unroll
    for (int q2 = 0; q2 < 8; ++q2) tacc = fmaf(graw[j * 16 + 8 + q2], at[q2], tacc);
    float sim = ahat * tacc;
    sim += __shfl_xor(sim, 1, 8);
    sim += __shfl_xor(sim, 2, 8);
    sim += __shfl_xor(sim, 4, 8);
    if (t16 == 0) out[p] = sim;
}

extern "C" void kernel_launch(void* const* d_in, const int* in_sizes, int n_in,
                              void* d_out, int out_size, void* d_ws, size_t ws_size,
                              hipStream_t stream) {
    const float* sup = (const float*)d_in[0];   // [25,64,8,2048] f32
    const float* tgt = (const float*)d_in[1];   // [64,8,2048] f32
    float* ws = (float*)d_ws;                   // needs 324608 floats = 1.3 MB
    float* out = (float*)d_out;                 // [25,64] f32
    gram_kernel<<<NPAIR * 2, 512, 0, stream>>>(sup, tgt, ws);
    solve_kernel<<<SOLVE_BLKS, 256, 0, stream>>>(ws, out);
}